// Round 2
// baseline (6127.716 us; speedup 1.0000x reference)
//
#include <hip/hip_runtime.h>

#define Hh 128
#define Ww 256
#define Cc 64
#define COUT 64
#define Bb 4
#define HW (Hh*Ww)

// Pre-transpose weight (Cout, C, 3, 3) -> wt[k][c][o] so the hot loop's
// weight reads are lane-uniform and contiguous in o (scalar-load friendly).
__global__ void wtrans(const float* __restrict__ wsrc, float* __restrict__ wdst) {
    int i = blockIdx.x * 256 + threadIdx.x;
    if (i >= COUT * Cc * 9) return;
    int k = i % 9;
    int c = (i / 9) % Cc;
    int o = i / (9 * Cc);
    wdst[(k * Cc + c) * COUT + o] = wsrc[i];
}

// Block = 256 threads covering 64w x 2h positions x 2 c-halves.
// threads [0,128): c in [0,32); threads [128,256): c in [32,64).
// Final acc reduced pairwise through LDS. Grid = 1024 blocks -> 4 blocks/CU.
__launch_bounds__(256, 4)
__global__ void dcn_kernel(const float* __restrict__ x,
                           const float* __restrict__ offset,
                           const float* __restrict__ wt,
                           const float* __restrict__ bias,
                           float* __restrict__ out) {
    __shared__ float red[COUT][128];   // [o][pos_local]: lane runs over pos -> no bank conflict

    const int tid = threadIdx.x;
    const int lane = tid & 63;
    const int hrow = (tid >> 6) & 1;
    const int chalf = tid >> 7;
    const int pos_local = tid & 127;

    const int w = blockIdx.x * 64 + lane;    // lanes along w: coalesced
    const int h = blockIdx.y * 2 + hrow;
    const int b = blockIdx.z;

    float acc[COUT];
#pragma unroll
    for (int o = 0; o < COUT; ++o) acc[o] = 0.f;

    const float* xb = x + b * Cc * HW + chalf * 32 * HW;
    const float* offb = offset + b * 18 * HW;
    const int pix = h * Ww + w;

    for (int ki = 0; ki < 3; ++ki) {
        for (int kj = 0; kj < 3; ++kj) {
            const int k = ki * 3 + kj;
            const float dy = offb[(2 * k) * HW + pix];
            const float dx = offb[(2 * k + 1) * HW + pix];
            const float py = (float)(h - 1 + ki) + dy;
            const float px = (float)(w - 1 + kj) + dx;
            const float y0f = floorf(py), x0f = floorf(px);
            const int y0 = (int)y0f, x0 = (int)x0f;
            const float ly = py - y0f, lx = px - x0f;
            const int y1 = y0 + 1, x1 = x0 + 1;
            const bool vy0 = ((unsigned)y0 < Hh), vy1 = ((unsigned)y1 < Hh);
            const bool vx0 = ((unsigned)x0 < Ww), vx1 = ((unsigned)x1 < Ww);
            float w00 = (1.f - ly) * (1.f - lx); if (!(vy0 && vx0)) w00 = 0.f;
            float w01 = (1.f - ly) * lx;         if (!(vy0 && vx1)) w01 = 0.f;
            float w10 = ly * (1.f - lx);         if (!(vy1 && vx0)) w10 = 0.f;
            float w11 = ly * lx;                 if (!(vy1 && vx1)) w11 = 0.f;
            const int y0c = min(max(y0, 0), Hh - 1), y1c = min(max(y1, 0), Hh - 1);
            const int x0c = min(max(x0, 0), Ww - 1), x1c = min(max(x1, 0), Ww - 1);
            const int a00 = y0c * Ww + x0c, a01 = y0c * Ww + x1c;
            const int a10 = y1c * Ww + x0c, a11 = y1c * Ww + x1c;

            const float* wk = wt + (k * Cc + chalf * 32) * COUT;
            const float* xc = xb;
            // software-pipelined gather: prefetch next c's 4 corners
            float p00 = xc[a00], p01 = xc[a01], p10 = xc[a10], p11 = xc[a11];
#pragma unroll 4
            for (int c = 0; c < 32; ++c) {
                const float v = w00 * p00 + w01 * p01 + w10 * p10 + w11 * p11;
                if (c < 31) {
                    const float* xn = xc + HW;
                    p00 = xn[a00]; p01 = xn[a01]; p10 = xn[a10]; p11 = xn[a11];
                }
                const float* wp = wk + c * COUT;   // lane-uniform -> s_load
#pragma unroll
                for (int o = 0; o < COUT; ++o)
                    acc[o] = fmaf(v, wp[o], acc[o]);
                xc += HW;
            }
        }
    }

    // pairwise reduction of the two c-halves through LDS
    if (chalf == 1) {
#pragma unroll
        for (int o = 0; o < COUT; ++o) red[o][pos_local] = acc[o];
    }
    __syncthreads();
    if (chalf == 0) {
        float* op = out + b * COUT * HW + pix;
#pragma unroll
        for (int o = 0; o < COUT; ++o)
            op[o * HW] = acc[o] + red[o][pos_local] + bias[o];
    }
}

extern "C" void kernel_launch(void* const* d_in, const int* in_sizes, int n_in,
                              void* d_out, int out_size, void* d_ws, size_t ws_size,
                              hipStream_t stream) {
    const float* x      = (const float*)d_in[0];
    const float* offset = (const float*)d_in[1];
    const float* weight = (const float*)d_in[2];
    const float* bias   = (const float*)d_in[3];
    float* out = (float*)d_out;
    float* wt  = (float*)d_ws;   // 9*64*64 floats = 144 KiB scratch

    wtrans<<<dim3((COUT * Cc * 9 + 255) / 256), 256, 0, stream>>>(weight, wt);
    dcn_kernel<<<dim3(Ww / 64, Hh / 2, Bb), 256, 0, stream>>>(x, offset, wt, bias, out);
}

// Round 3
// 358.463 us; speedup vs baseline: 17.0944x; 17.0944x over previous
//
#include <hip/hip_runtime.h>

typedef short short8 __attribute__((ext_vector_type(8)));
typedef float floatx4 __attribute__((ext_vector_type(4)));

#define Hh 128
#define Ww 256
#define Cc 64
#define COUT 64
#define Bb 4
#define HW (Hh*Ww)
#define VPAD 72   // LDS V row stride in bf16 elements (64 + 8 pad)

__device__ inline unsigned bf16rne(float f) {
    unsigned u = __float_as_uint(f);
    return (u + 0x7FFF + ((u >> 16) & 1)) >> 16;
}

// weight (o, c, kt) fp32 -> Wb[kt][o][c] bf16 (A-operand friendly: c contiguous)
__global__ void wtrans(const float* __restrict__ src, unsigned short* __restrict__ dst) {
    int i = blockIdx.x * 256 + threadIdx.x;
    if (i >= COUT * Cc * 9) return;
    int kt = i % 9, c = (i / 9) % Cc, o = i / (9 * Cc);
    dst[(kt * COUT + o) * Cc + c] = (unsigned short)bf16rne(src[i]);
}

// Implicit GEMM: out[o][pos] = sum_{kt,c} W[o][kt,c] * V[kt,c][pos]
// Block: 256 thr = 4 waves; tile = 64 o x 128 pos (one h-row, 128 consecutive w).
// Per tap kt: gather V[64c][128p] bilinear samples -> LDS (bf16), then
// 2 MFMA k-steps (c-groups of 32) per wave over 4 m-tiles x 2 n-tiles.
__launch_bounds__(256, 4)
__global__ void dcn_mfma(const float* __restrict__ x,
                         const float* __restrict__ offset,
                         const unsigned short* __restrict__ wb,
                         const float* __restrict__ bias,
                         float* __restrict__ out) {
    __shared__ unsigned short V[128 * VPAD];   // [p][c] bf16, 18432 B

    const int tid = threadIdx.x;
    const int p   = tid & 127;    // position within strip (gather role)
    const int cg  = tid >> 7;     // gathers c in [cg*32, cg*32+32)
    const int wv  = tid >> 6;     // wave id 0..3 (MFMA role: p in [wv*32, wv*32+32))
    const int ln  = tid & 63;

    const int b  = blockIdx.z;
    const int h  = blockIdx.y;
    const int w0 = blockIdx.x * 128;
    const int w  = w0 + p;

    const float* xb   = x + b * Cc * HW + cg * 32 * HW;
    const float* offb = offset + b * 18 * HW + h * Ww + w;

    floatx4 acc[4][2];
#pragma unroll
    for (int mt = 0; mt < 4; ++mt)
#pragma unroll
        for (int nt = 0; nt < 2; ++nt) acc[mt][nt] = (floatx4)0.f;

    for (int kt = 0; kt < 9; ++kt) {
        const int ki = kt / 3, kj = kt % 3;
        // ---- per-position bilinear setup (once per tap) ----
        const float dy = offb[(2 * kt) * HW];
        const float dx = offb[(2 * kt + 1) * HW];
        const float py = (float)(h - 1 + ki) + dy;
        const float px = (float)(w - 1 + kj) + dx;
        const float y0f = floorf(py), x0f = floorf(px);
        const int y0 = (int)y0f, x0 = (int)x0f;
        const float ly = py - y0f, lx = px - x0f;
        const int y1 = y0 + 1, x1 = x0 + 1;
        const bool vy0 = ((unsigned)y0 < Hh), vy1 = ((unsigned)y1 < Hh);
        const bool vx0 = ((unsigned)x0 < Ww), vx1 = ((unsigned)x1 < Ww);
        float w00 = (1.f - ly) * (1.f - lx); if (!(vy0 && vx0)) w00 = 0.f;
        float w01 = (1.f - ly) * lx;         if (!(vy0 && vx1)) w01 = 0.f;
        float w10 = ly * (1.f - lx);         if (!(vy1 && vx0)) w10 = 0.f;
        float w11 = ly * lx;                 if (!(vy1 && vx1)) w11 = 0.f;
        const int y0c = min(max(y0, 0), Hh - 1), y1c = min(max(y1, 0), Hh - 1);
        const int x0c = min(max(x0, 0), Ww - 1), x1c = min(max(x1, 0), Ww - 1);
        const int a00 = y0c * Ww + x0c, a01 = y0c * Ww + x1c;
        const int a10 = y1c * Ww + x0c, a11 = y1c * Ww + x1c;

        if (kt > 0) __syncthreads();   // V consumed by previous tap's MFMA
        // ---- gather: 32 c's for position p -> V[p][cg*32 ..] ----
        unsigned short* vdst = &V[p * VPAD + cg * 32];
#pragma unroll 1
        for (int cc = 0; cc < 32; cc += 8) {
            unsigned pk[4];
#pragma unroll
            for (int j = 0; j < 8; j += 2) {
                const float* x0p = xb + (cc + j) * HW;
                const float* x1p = x0p + HW;
                float v0 = w00 * x0p[a00] + w01 * x0p[a01] + w10 * x0p[a10] + w11 * x0p[a11];
                float v1 = w00 * x1p[a00] + w01 * x1p[a01] + w10 * x1p[a10] + w11 * x1p[a11];
                pk[j >> 1] = bf16rne(v0) | (bf16rne(v1) << 16);
            }
            uint4 u; u.x = pk[0]; u.y = pk[1]; u.z = pk[2]; u.w = pk[3];
            *(uint4*)(vdst + cc) = u;   // ds_write_b128, 16B aligned
        }
        __syncthreads();

        // ---- MFMA phase: 2 k-steps of K=32 ----
        const unsigned short* wk = wb + kt * COUT * Cc;
#pragma unroll
        for (int g = 0; g < 2; ++g) {
            short8 bfrag[2];
#pragma unroll
            for (int nt = 0; nt < 2; ++nt) {
                const int pp = wv * 32 + nt * 16 + (ln & 15);
                bfrag[nt] = *(const short8*)&V[pp * VPAD + g * 32 + (ln >> 4) * 8];
            }
#pragma unroll
            for (int mt = 0; mt < 4; ++mt) {
                const int oo = mt * 16 + (ln & 15);
                short8 afrag = *(const short8*)(wk + oo * Cc + g * 32 + (ln >> 4) * 8);
#pragma unroll
                for (int nt = 0; nt < 2; ++nt)
                    acc[mt][nt] = __builtin_amdgcn_mfma_f32_16x16x32_bf16(
                        afrag, bfrag[nt], acc[mt][nt], 0, 0, 0);
            }
        }
    }

    // ---- epilogue: C/D layout col=lane&15 (pos), row=(lane>>4)*4+reg (o) ----
    float* outp = out + b * COUT * HW + h * Ww;
#pragma unroll
    for (int mt = 0; mt < 4; ++mt)
#pragma unroll
        for (int nt = 0; nt < 2; ++nt) {
            const int col = w0 + wv * 32 + nt * 16 + (ln & 15);
#pragma unroll
            for (int r = 0; r < 4; ++r) {
                const int o = mt * 16 + (ln >> 4) * 4 + r;
                outp[o * HW + col] = acc[mt][nt][r] + bias[o];
            }
        }
}

extern "C" void kernel_launch(void* const* d_in, const int* in_sizes, int n_in,
                              void* d_out, int out_size, void* d_ws, size_t ws_size,
                              hipStream_t stream) {
    const float* x      = (const float*)d_in[0];
    const float* offset = (const float*)d_in[1];
    const float* weight = (const float*)d_in[2];
    const float* bias   = (const float*)d_in[3];
    float* out = (float*)d_out;
    unsigned short* wb = (unsigned short*)d_ws;   // 9*64*64 bf16 = 72 KiB

    wtrans<<<dim3((COUT * Cc * 9 + 255) / 256), 256, 0, stream>>>(weight, wb);
    dcn_mfma<<<dim3(Ww / 128, Hh, Bb), 256, 0, stream>>>(x, offset, wb, bias, out);
}

// Round 4
// 306.994 us; speedup vs baseline: 19.9604x; 1.1677x over previous
//
#include <hip/hip_runtime.h>

typedef short short8 __attribute__((ext_vector_type(8)));
typedef float floatx4 __attribute__((ext_vector_type(4)));

#define Hh 128
#define Ww 256
#define Cc 64
#define COUT 64
#define Bb 4
#define HW (Hh*Ww)
#define VPAD 72   // LDS V row stride in bf16 elements (64 + 8 pad)

__device__ inline unsigned bf16rne(float f) {
    unsigned u = __float_as_uint(f);
    return (u + 0x7FFF + ((u >> 16) & 1)) >> 16;
}

// weight (o, c, kt) fp32 -> Wb[kt][o][c] bf16 (A-operand friendly: c contiguous)
__global__ void wtrans(const float* __restrict__ src, unsigned short* __restrict__ dst) {
    int i = blockIdx.x * 256 + threadIdx.x;
    if (i >= COUT * Cc * 9) return;
    int kt = i % 9, c = (i / 9) % Cc, o = i / (9 * Cc);
    dst[(kt * COUT + o) * Cc + c] = (unsigned short)bf16rne(src[i]);
}

// x NCHW -> NHWC via LDS transpose. Block: one (b, h, 64-w) tile, all 64 c.
__global__ void xtrans(const float* __restrict__ src, float* __restrict__ dst) {
    __shared__ float t[64][65];
    const int bx = blockIdx.x;          // w-tile 0..3
    const int h  = blockIdx.y;
    const int b  = blockIdx.z;
    const int tid = threadIdx.x;
    const int wl = tid & 63;            // lane along w (coalesced read)
    const int q  = tid >> 6;            // 0..3
    const float* sp = src + (b * Cc * Hh + h) * Ww + bx * 64 + wl;
#pragma unroll
    for (int i = 0; i < 16; ++i) {
        const int c = q * 16 + i;
        t[c][wl] = sp[c * HW];
    }
    __syncthreads();
    const int cl = tid & 63;            // lane along c (coalesced write)
    float* dp = dst + ((size_t)(b * Hh + h) * Ww + bx * 64) * 64 + cl;
#pragma unroll
    for (int i = 0; i < 16; ++i) {
        const int wq = q * 16 + i;
        dp[wq * 64] = t[cl][wq];
    }
}

// Implicit GEMM: out[o][pos] = sum_{kt,c} W[o][kt,c] * V[kt,c][pos]
// Block: 256 thr = 4 waves; tile = 64 o x 128 pos (one h-row, 128 consecutive w).
// Per tap kt: NHWC bilinear gather -> LDS V (bf16), then 2 MFMA k-steps.
__launch_bounds__(256, 3)
__global__ void dcn_mfma(const float* __restrict__ xn,       // NHWC
                         const float* __restrict__ offset,
                         const unsigned short* __restrict__ wb,
                         const float* __restrict__ bias,
                         float* __restrict__ out) {
    __shared__ unsigned short V[128 * VPAD];   // [p][c] bf16, 18432 B

    const int tid = threadIdx.x;
    const int p   = tid & 127;    // position within strip (gather role)
    const int cg  = tid >> 7;     // gathers c in [cg*32, cg*32+32)
    const int wv  = tid >> 6;     // wave id 0..3 (MFMA role)
    const int ln  = tid & 63;

    const int b  = blockIdx.z;
    const int h  = blockIdx.y;
    const int w0 = blockIdx.x * 128;
    const int w  = w0 + p;

    const float* xb   = xn + (size_t)b * HW * 64;          // [y][x][c]
    const float* offb = offset + b * 18 * HW + h * Ww + w;

    floatx4 acc[4][2];
#pragma unroll
    for (int mt = 0; mt < 4; ++mt)
#pragma unroll
        for (int nt = 0; nt < 2; ++nt) acc[mt][nt] = (floatx4)0.f;

    for (int kt = 0; kt < 9; ++kt) {
        const int ki = kt / 3, kj = kt % 3;
        // ---- per-position bilinear setup (once per tap) ----
        const float dy = offb[(2 * kt) * HW];
        const float dx = offb[(2 * kt + 1) * HW];
        const float py = (float)(h - 1 + ki) + dy;
        const float px = (float)(w - 1 + kj) + dx;
        const float y0f = floorf(py), x0f = floorf(px);
        const int y0 = (int)y0f, x0 = (int)x0f;
        const float ly = py - y0f, lx = px - x0f;
        const int y1 = y0 + 1, x1 = x0 + 1;
        const bool vy0 = ((unsigned)y0 < Hh), vy1 = ((unsigned)y1 < Hh);
        const bool vx0 = ((unsigned)x0 < Ww), vx1 = ((unsigned)x1 < Ww);
        float w00 = (1.f - ly) * (1.f - lx); if (!(vy0 && vx0)) w00 = 0.f;
        float w01 = (1.f - ly) * lx;         if (!(vy0 && vx1)) w01 = 0.f;
        float w10 = ly * (1.f - lx);         if (!(vy1 && vx0)) w10 = 0.f;
        float w11 = ly * lx;                 if (!(vy1 && vx1)) w11 = 0.f;
        const int y0c = min(max(y0, 0), Hh - 1), y1c = min(max(y1, 0), Hh - 1);
        const int x0c = min(max(x0, 0), Ww - 1), x1c = min(max(x1, 0), Ww - 1);
        const int a00 = (y0c * Ww + x0c) * 64 + cg * 32;
        const int a01 = (y0c * Ww + x1c) * 64 + cg * 32;
        const int a10 = (y1c * Ww + x0c) * 64 + cg * 32;
        const int a11 = (y1c * Ww + x1c) * 64 + cg * 32;

        if (kt > 0) __syncthreads();   // V consumed by previous tap's MFMA

        // ---- gather: 32 contiguous channels per corner (float4 x 8) ----
        floatx4 vv[8];
#pragma unroll
        for (int j = 0; j < 8; ++j) {
            const floatx4 c00 = *(const floatx4*)(xb + a00 + j * 4);
            const floatx4 c01 = *(const floatx4*)(xb + a01 + j * 4);
            const floatx4 c10 = *(const floatx4*)(xb + a10 + j * 4);
            const floatx4 c11 = *(const floatx4*)(xb + a11 + j * 4);
            vv[j] = w00 * c00 + w01 * c01 + w10 * c10 + w11 * c11;
        }
        unsigned short* vdst = &V[p * VPAD + cg * 32];
#pragma unroll
        for (int j = 0; j < 8; j += 2) {
            uint4 u;
            u.x = bf16rne(vv[j][0])     | (bf16rne(vv[j][1]) << 16);
            u.y = bf16rne(vv[j][2])     | (bf16rne(vv[j][3]) << 16);
            u.z = bf16rne(vv[j + 1][0]) | (bf16rne(vv[j + 1][1]) << 16);
            u.w = bf16rne(vv[j + 1][2]) | (bf16rne(vv[j + 1][3]) << 16);
            *(uint4*)(vdst + j * 4) = u;   // ds_write_b128
        }
        __syncthreads();

        // ---- MFMA phase: 2 k-steps of K=32 ----
        const unsigned short* wk = wb + kt * COUT * Cc;
#pragma unroll
        for (int g = 0; g < 2; ++g) {
            short8 bfrag[2];
#pragma unroll
            for (int nt = 0; nt < 2; ++nt) {
                const int pp = wv * 32 + nt * 16 + (ln & 15);
                bfrag[nt] = *(const short8*)&V[pp * VPAD + g * 32 + (ln >> 4) * 8];
            }
#pragma unroll
            for (int mt = 0; mt < 4; ++mt) {
                const int oo = mt * 16 + (ln & 15);
                short8 afrag = *(const short8*)(wk + oo * Cc + g * 32 + (ln >> 4) * 8);
#pragma unroll
                for (int nt = 0; nt < 2; ++nt)
                    acc[mt][nt] = __builtin_amdgcn_mfma_f32_16x16x32_bf16(
                        afrag, bfrag[nt], acc[mt][nt], 0, 0, 0);
            }
        }
    }

    // ---- epilogue: C/D layout col=lane&15 (pos), row=(lane>>4)*4+reg (o) ----
    float* outp = out + b * COUT * HW + h * Ww;
#pragma unroll
    for (int mt = 0; mt < 4; ++mt)
#pragma unroll
        for (int nt = 0; nt < 2; ++nt) {
            const int col = w0 + wv * 32 + nt * 16 + (ln & 15);
#pragma unroll
            for (int r = 0; r < 4; ++r) {
                const int o = mt * 16 + (ln >> 4) * 4 + r;
                outp[o * HW + col] = acc[mt][nt][r] + bias[o];
            }
        }
}

extern "C" void kernel_launch(void* const* d_in, const int* in_sizes, int n_in,
                              void* d_out, int out_size, void* d_ws, size_t ws_size,
                              hipStream_t stream) {
    const float* x      = (const float*)d_in[0];
    const float* offset = (const float*)d_in[1];
    const float* weight = (const float*)d_in[2];
    const float* bias   = (const float*)d_in[3];
    float* out = (float*)d_out;

    float* xn = (float*)d_ws;                                   // 32 MiB NHWC
    unsigned short* wb = (unsigned short*)((char*)d_ws + (size_t)Bb * HW * Cc * 4);

    wtrans<<<dim3((COUT * Cc * 9 + 255) / 256), 256, 0, stream>>>(weight, wb);
    xtrans<<<dim3(Ww / 64, Hh, Bb), 256, 0, stream>>>(x, xn);
    dcn_mfma<<<dim3(Ww / 128, Hh, Bb), 256, 0, stream>>>(xn, offset, wb, bias, out);
}

// Round 5
// 230.014 us; speedup vs baseline: 26.6406x; 1.3347x over previous
//
#include <hip/hip_runtime.h>

typedef short short8 __attribute__((ext_vector_type(8)));
typedef float floatx4 __attribute__((ext_vector_type(4)));
typedef _Float16 half2v __attribute__((ext_vector_type(2)));

#define Hh 128
#define Ww 256
#define Cc 64
#define COUT 64
#define Bb 4
#define HW (Hh*Ww)
#define VPAD 72   // LDS V row stride in bf16 elements (64 + 8 pad)

__device__ inline unsigned bf16rne(float f) {
    unsigned u = __float_as_uint(f);
    return (u + 0x7FFF + ((u >> 16) & 1)) >> 16;
}

// weight (o, c, kt) fp32 -> Wb[kt][o][c] bf16 (A-operand friendly: c contiguous)
__global__ void wtrans(const float* __restrict__ src, unsigned short* __restrict__ dst) {
    int i = blockIdx.x * 256 + threadIdx.x;
    if (i >= COUT * Cc * 9) return;
    int kt = i % 9, c = (i / 9) % Cc, o = i / (9 * Cc);
    dst[(kt * COUT + o) * Cc + c] = (unsigned short)bf16rne(src[i]);
}

// x NCHW fp32 -> NHWC fp16 via LDS transpose. Block: one (b, h, 64-w) tile.
__global__ void xtrans(const float* __restrict__ src, _Float16* __restrict__ dst) {
    __shared__ float t[64][65];
    const int bx = blockIdx.x, h = blockIdx.y, b = blockIdx.z;
    const int tid = threadIdx.x;
    const int wl = tid & 63;            // lane along w (coalesced read)
    const int q  = tid >> 6;            // 0..3
    const float* sp = src + (b * Cc * Hh + h) * Ww + bx * 64 + wl;
#pragma unroll
    for (int i = 0; i < 16; ++i) t[q * 16 + i][wl] = sp[(q * 16 + i) * HW];
    __syncthreads();
    // write: lane = channel-pair (coalesced), 8 positions per thread
    const int cl5 = tid & 31;
    const int pq  = tid >> 5;           // 0..7
    unsigned* dstu = (unsigned*)dst;
    const size_t pbase = ((size_t)(b * Hh + h) * Ww + bx * 64);
#pragma unroll
    for (int i = 0; i < 8; ++i) {
        const int wq = pq * 8 + i;
        half2v hv;
        hv.x = (_Float16)t[2 * cl5][wq];
        hv.y = (_Float16)t[2 * cl5 + 1][wq];
        dstu[(pbase + wq) * 32 + cl5] = *(unsigned*)&hv;
    }
}

struct Tap {
    float w00, w01, w10, w11;
    int a00, a01, a10, a11;   // corner addresses in uint4 (16B) units
};

__device__ inline void tap_setup(int kt, int h, int w, const float* __restrict__ offb,
                                 int cg, Tap& t) {
    const int ki = kt / 3, kj = kt % 3;
    const float dy = offb[(2 * kt) * HW];
    const float dx = offb[(2 * kt + 1) * HW];
    const float py = (float)(h - 1 + ki) + dy;
    const float px = (float)(w - 1 + kj) + dx;
    const float y0f = floorf(py), x0f = floorf(px);
    const int y0 = (int)y0f, x0 = (int)x0f;
    const float ly = py - y0f, lx = px - x0f;
    const int y1 = y0 + 1, x1 = x0 + 1;
    const bool vy0 = ((unsigned)y0 < Hh), vy1 = ((unsigned)y1 < Hh);
    const bool vx0 = ((unsigned)x0 < Ww), vx1 = ((unsigned)x1 < Ww);
    t.w00 = (vy0 && vx0) ? (1.f - ly) * (1.f - lx) : 0.f;
    t.w01 = (vy0 && vx1) ? (1.f - ly) * lx : 0.f;
    t.w10 = (vy1 && vx0) ? ly * (1.f - lx) : 0.f;
    t.w11 = (vy1 && vx1) ? ly * lx : 0.f;
    const int y0c = min(max(y0, 0), Hh - 1), y1c = min(max(y1, 0), Hh - 1);
    const int x0c = min(max(x0, 0), Ww - 1), x1c = min(max(x1, 0), Ww - 1);
    t.a00 = (y0c * Ww + x0c) * 8 + cg * 4;   // 64ch*2B = 8 uint4 per position
    t.a01 = (y0c * Ww + x1c) * 8 + cg * 4;
    t.a10 = (y1c * Ww + x0c) * 8 + cg * 4;
    t.a11 = (y1c * Ww + x1c) * 8 + cg * 4;
}

__device__ inline void tap_load(const uint4* __restrict__ xb4, const Tap& t,
                                unsigned pf[64]) {
#pragma unroll
    for (int j = 0; j < 4; ++j) {
        *(uint4*)&pf[(0 * 4 + j) * 4] = xb4[t.a00 + j];
        *(uint4*)&pf[(1 * 4 + j) * 4] = xb4[t.a01 + j];
        *(uint4*)&pf[(2 * 4 + j) * 4] = xb4[t.a10 + j];
        *(uint4*)&pf[(3 * 4 + j) * 4] = xb4[t.a11 + j];
    }
}

__device__ inline void tap_store(const Tap& t, const unsigned pf[64],
                                 unsigned short* __restrict__ vrow) {
#pragma unroll
    for (int j = 0; j < 4; ++j) {
        unsigned o[4];
#pragma unroll
        for (int s = 0; s < 4; ++s) {
            const half2v h00 = *(const half2v*)&pf[(0 * 4 + j) * 4 + s];
            const half2v h01 = *(const half2v*)&pf[(1 * 4 + j) * 4 + s];
            const half2v h10 = *(const half2v*)&pf[(2 * 4 + j) * 4 + s];
            const half2v h11 = *(const half2v*)&pf[(3 * 4 + j) * 4 + s];
            const float vlo = t.w00 * (float)h00.x + t.w01 * (float)h01.x
                            + t.w10 * (float)h10.x + t.w11 * (float)h11.x;
            const float vhi = t.w00 * (float)h00.y + t.w01 * (float)h01.y
                            + t.w10 * (float)h10.y + t.w11 * (float)h11.y;
            o[s] = bf16rne(vlo) | (bf16rne(vhi) << 16);
        }
        uint4 u; u.x = o[0]; u.y = o[1]; u.z = o[2]; u.w = o[3];
        *(uint4*)(vrow + j * 8) = u;   // ds_write_b128, channels j*8..j*8+7
    }
}

__device__ inline void mfma_tap(const unsigned short* __restrict__ wk,
                                const unsigned short* __restrict__ Vbuf,
                                int wv, int ln, floatx4 acc[4][2]) {
#pragma unroll
    for (int g = 0; g < 2; ++g) {
        short8 bfrag[2];
#pragma unroll
        for (int nt = 0; nt < 2; ++nt) {
            const int pp = wv * 32 + nt * 16 + (ln & 15);
            bfrag[nt] = *(const short8*)&Vbuf[pp * VPAD + g * 32 + (ln >> 4) * 8];
        }
#pragma unroll
        for (int mt = 0; mt < 4; ++mt) {
            const int oo = mt * 16 + (ln & 15);
            short8 afrag = *(const short8*)(wk + oo * Cc + g * 32 + (ln >> 4) * 8);
#pragma unroll
            for (int nt = 0; nt < 2; ++nt)
                acc[mt][nt] = __builtin_amdgcn_mfma_f32_16x16x32_bf16(
                    afrag, bfrag[nt], acc[mt][nt], 0, 0, 0);
        }
    }
}

// Implicit GEMM, software-pipelined over taps with double-buffered LDS V.
__launch_bounds__(256, 3)
__global__ void dcn_mfma(const _Float16* __restrict__ xn,   // NHWC fp16
                         const float* __restrict__ offset,
                         const unsigned short* __restrict__ wb,
                         const float* __restrict__ bias,
                         float* __restrict__ out) {
    __shared__ unsigned short V[2][128 * VPAD];   // 2 x 18432 B

    const int tid = threadIdx.x;
    const int p   = tid & 127;
    const int cg  = tid >> 7;
    const int wv  = tid >> 6;
    const int ln  = tid & 63;

    const int b  = blockIdx.z;
    const int h  = blockIdx.y;
    const int w0 = blockIdx.x * 128;
    const int w  = w0 + p;

    const uint4* xb4  = (const uint4*)(xn + (size_t)b * HW * 64);
    const float* offb = offset + b * 18 * HW + h * Ww + w;
    unsigned short* vrow0 = &V[0][p * VPAD + cg * 32];
    unsigned short* vrow1 = &V[1][p * VPAD + cg * 32];

    floatx4 acc[4][2];
#pragma unroll
    for (int mt = 0; mt < 4; ++mt)
#pragma unroll
        for (int nt = 0; nt < 2; ++nt) acc[mt][nt] = (floatx4)0.f;

    unsigned pf[64];
    Tap t;

    // prologue: tap 0
    tap_setup(0, h, w, offb, cg, t);
    tap_load(xb4, t, pf);
    tap_store(t, pf, vrow0);
    __syncthreads();

    // pipeline: issue loads for tap kt, MFMA tap kt-1, pack tap kt, barrier
#pragma unroll 1
    for (int kt = 1; kt < 9; ++kt) {
        tap_setup(kt, h, w, offb, cg, t);
        tap_load(xb4, t, pf);                              // loads in flight
        mfma_tap(wb + (kt - 1) * COUT * Cc, V[(kt - 1) & 1], wv, ln, acc);
        tap_store(t, pf, (kt & 1) ? vrow1 : vrow0);        // waits loads here
        __syncthreads();
    }
    // epilogue: tap 8 MFMA
    mfma_tap(wb + 8 * COUT * Cc, V[0], wv, ln, acc);

    // epilogue: C/D layout col=lane&15 (pos), row=(lane>>4)*4+reg (o)
    float* outp = out + b * COUT * HW + h * Ww;
#pragma unroll
    for (int mt = 0; mt < 4; ++mt)
#pragma unroll
        for (int nt = 0; nt < 2; ++nt) {
            const int col = w0 + wv * 32 + nt * 16 + (ln & 15);
#pragma unroll
            for (int r = 0; r < 4; ++r) {
                const int o = mt * 16 + (ln >> 4) * 4 + r;
                outp[o * HW + col] = acc[mt][nt][r] + bias[o];
            }
        }
}

extern "C" void kernel_launch(void* const* d_in, const int* in_sizes, int n_in,
                              void* d_out, int out_size, void* d_ws, size_t ws_size,
                              hipStream_t stream) {
    const float* x      = (const float*)d_in[0];
    const float* offset = (const float*)d_in[1];
    const float* weight = (const float*)d_in[2];
    const float* bias   = (const float*)d_in[3];
    float* out = (float*)d_out;

    _Float16* xn = (_Float16*)d_ws;                          // 16.8 MiB NHWC fp16
    unsigned short* wb = (unsigned short*)((char*)d_ws + (size_t)Bb * HW * Cc * 2);

    wtrans<<<dim3((COUT * Cc * 9 + 255) / 256), 256, 0, stream>>>(weight, wb);
    xtrans<<<dim3(Ww / 64, Hh, Bb), 256, 0, stream>>>(x, xn);
    dcn_mfma<<<dim3(Ww / 128, Hh, Bb), 256, 0, stream>>>(xn, offset, wb, bias, out);
}

// Round 6
// 215.071 us; speedup vs baseline: 28.4916x; 1.0695x over previous
//
#include <hip/hip_runtime.h>

typedef short short8 __attribute__((ext_vector_type(8)));
typedef float floatx4 __attribute__((ext_vector_type(4)));
typedef _Float16 half2v __attribute__((ext_vector_type(2)));

#define Hh 128
#define Ww 256
#define Cc 64
#define COUT 64
#define Bb 4
#define HW (Hh*Ww)
#define VPAD 72   // LDS V row stride in bf16 elements (64 + 8 pad)

__device__ inline unsigned bf16rne(float f) {
    unsigned u = __float_as_uint(f);
    return (u + 0x7FFF + ((u >> 16) & 1)) >> 16;
}

// weight (o, c, kt) fp32 -> Wb[kt][o][c] bf16 (A-operand friendly: c contiguous)
__global__ void wtrans(const float* __restrict__ src, unsigned short* __restrict__ dst) {
    int i = blockIdx.x * 256 + threadIdx.x;
    if (i >= COUT * Cc * 9) return;
    int kt = i % 9, c = (i / 9) % Cc, o = i / (9 * Cc);
    dst[(kt * COUT + o) * Cc + c] = (unsigned short)bf16rne(src[i]);
}

// x NCHW fp32 -> NHWC fp16. One block per (h,b) row: reads 64 coalesced 1KB
// rows, writes one contiguous 32KB NHWC row as coalesced dwordx4.
__global__ void xtrans(const float* __restrict__ src, _Float16* __restrict__ dst) {
    __shared__ unsigned short T[256][VPAD];   // [pos][ch] fp16, row=144B (16B-aligned)
    const int h = blockIdx.x, b = blockIdx.y;
    const int tid = threadIdx.x;
    const float* sp = src + (b * Cc * Hh + h) * Ww + tid;   // x[b][.][h][tid]
#pragma unroll
    for (int c2 = 0; c2 < 32; ++c2) {
        const float v0 = sp[(2 * c2) * HW];
        const float v1 = sp[(2 * c2 + 1) * HW];
        half2v hv; hv.x = (_Float16)v0; hv.y = (_Float16)v1;
        *(unsigned*)&T[tid][2 * c2] = *(unsigned*)&hv;
    }
    __syncthreads();
    uint4* drow = (uint4*)(dst + ((size_t)(b * Hh + h) * Ww) * 64);  // 2048 uint4
#pragma unroll
    for (int j = 0; j < 8; ++j) {
        const int idx = j * 256 + tid;        // contiguous 4KB per iteration
        drow[idx] = *(const uint4*)&T[idx >> 3][(idx & 7) * 8];
    }
}

struct Tap {
    float w00, w01, w10, w11;
    int a00, a01, a10, a11;   // corner addresses in uint4 (16B) units
};

__device__ inline void tap_setup(int kt, int h, int w, const float* __restrict__ offb,
                                 int cg, Tap& t) {
    const int ki = kt / 3, kj = kt % 3;
    const float dy = offb[(2 * kt) * HW];
    const float dx = offb[(2 * kt + 1) * HW];
    const float py = (float)(h - 1 + ki) + dy;
    const float px = (float)(w - 1 + kj) + dx;
    const float y0f = floorf(py), x0f = floorf(px);
    const int y0 = (int)y0f, x0 = (int)x0f;
    const float ly = py - y0f, lx = px - x0f;
    const int y1 = y0 + 1, x1 = x0 + 1;
    const bool vy0 = ((unsigned)y0 < Hh), vy1 = ((unsigned)y1 < Hh);
    const bool vx0 = ((unsigned)x0 < Ww), vx1 = ((unsigned)x1 < Ww);
    t.w00 = (vy0 && vx0) ? (1.f - ly) * (1.f - lx) : 0.f;
    t.w01 = (vy0 && vx1) ? (1.f - ly) * lx : 0.f;
    t.w10 = (vy1 && vx0) ? ly * (1.f - lx) : 0.f;
    t.w11 = (vy1 && vx1) ? ly * lx : 0.f;
    const int y0c = min(max(y0, 0), Hh - 1), y1c = min(max(y1, 0), Hh - 1);
    const int x0c = min(max(x0, 0), Ww - 1), x1c = min(max(x1, 0), Ww - 1);
    t.a00 = (y0c * Ww + x0c) * 8 + cg * 4;   // 64ch*2B = 8 uint4 per position
    t.a01 = (y0c * Ww + x1c) * 8 + cg * 4;
    t.a10 = (y1c * Ww + x0c) * 8 + cg * 4;
    t.a11 = (y1c * Ww + x1c) * 8 + cg * 4;
}

__device__ inline void tap_load(const uint4* __restrict__ xb4, const Tap& t,
                                unsigned pf[64]) {
#pragma unroll
    for (int j = 0; j < 4; ++j) {
        *(uint4*)&pf[(0 * 4 + j) * 4] = xb4[t.a00 + j];
        *(uint4*)&pf[(1 * 4 + j) * 4] = xb4[t.a01 + j];
        *(uint4*)&pf[(2 * 4 + j) * 4] = xb4[t.a10 + j];
        *(uint4*)&pf[(3 * 4 + j) * 4] = xb4[t.a11 + j];
    }
}

__device__ inline void tap_store(const Tap& t, const unsigned pf[64],
                                 unsigned short* __restrict__ vrow) {
#pragma unroll
    for (int j = 0; j < 4; ++j) {
        unsigned o[4];
#pragma unroll
        for (int s = 0; s < 4; ++s) {
            const half2v h00 = *(const half2v*)&pf[(0 * 4 + j) * 4 + s];
            const half2v h01 = *(const half2v*)&pf[(1 * 4 + j) * 4 + s];
            const half2v h10 = *(const half2v*)&pf[(2 * 4 + j) * 4 + s];
            const half2v h11 = *(const half2v*)&pf[(3 * 4 + j) * 4 + s];
            const float vlo = t.w00 * (float)h00.x + t.w01 * (float)h01.x
                            + t.w10 * (float)h10.x + t.w11 * (float)h11.x;
            const float vhi = t.w00 * (float)h00.y + t.w01 * (float)h01.y
                            + t.w10 * (float)h10.y + t.w11 * (float)h11.y;
            o[s] = bf16rne(vlo) | (bf16rne(vhi) << 16);
        }
        uint4 u; u.x = o[0]; u.y = o[1]; u.z = o[2]; u.w = o[3];
        *(uint4*)(vrow + j * 8) = u;   // ds_write_b128, channels j*8..j*8+7
    }
}

__device__ inline void mfma_tap(const unsigned short* __restrict__ wk,
                                const unsigned short* __restrict__ Vbuf,
                                int wv, int ln, floatx4 acc[4][2]) {
#pragma unroll
    for (int g = 0; g < 2; ++g) {
        short8 bfrag[2];
#pragma unroll
        for (int nt = 0; nt < 2; ++nt) {
            const int pp = wv * 32 + nt * 16 + (ln & 15);
            bfrag[nt] = *(const short8*)&Vbuf[pp * VPAD + g * 32 + (ln >> 4) * 8];
        }
#pragma unroll
        for (int mt = 0; mt < 4; ++mt) {
            const int oo = mt * 16 + (ln & 15);
            short8 afrag = *(const short8*)(wk + oo * Cc + g * 32 + (ln >> 4) * 8);
#pragma unroll
            for (int nt = 0; nt < 2; ++nt)
                acc[mt][nt] = __builtin_amdgcn_mfma_f32_16x16x32_bf16(
                    afrag, bfrag[nt], acc[mt][nt], 0, 0, 0);
        }
    }
}

// Implicit GEMM, software-pipelined over taps with double-buffered LDS V.
// launch_bounds(256,4): 4 blocks/CU resident (LDS 4x36.9KB=147KB fits 160KB;
// VGPR cap 128 >= 72 measured) -- grid is exactly 4 blocks/CU, all resident.
__launch_bounds__(256, 4)
__global__ void dcn_mfma(const _Float16* __restrict__ xn,   // NHWC fp16
                         const float* __restrict__ offset,
                         const unsigned short* __restrict__ wb,
                         const float* __restrict__ bias,
                         float* __restrict__ out) {
    __shared__ unsigned short V[2][128 * VPAD];   // 2 x 18432 B

    const int tid = threadIdx.x;
    const int p   = tid & 127;
    const int cg  = tid >> 7;
    const int wv  = tid >> 6;
    const int ln  = tid & 63;

    const int b  = blockIdx.z;
    const int h  = blockIdx.y;
    const int w0 = blockIdx.x * 128;
    const int w  = w0 + p;

    const uint4* xb4  = (const uint4*)(xn + (size_t)b * HW * 64);
    const float* offb = offset + b * 18 * HW + h * Ww + w;
    unsigned short* vrow0 = &V[0][p * VPAD + cg * 32];
    unsigned short* vrow1 = &V[1][p * VPAD + cg * 32];

    floatx4 acc[4][2];
#pragma unroll
    for (int mt = 0; mt < 4; ++mt)
#pragma unroll
        for (int nt = 0; nt < 2; ++nt) acc[mt][nt] = (floatx4)0.f;

    unsigned pf[64];
    Tap t;

    // prologue: tap 0
    tap_setup(0, h, w, offb, cg, t);
    tap_load(xb4, t, pf);
    tap_store(t, pf, vrow0);
    __syncthreads();

    // pipeline: issue loads for tap kt, MFMA tap kt-1, pack tap kt, barrier
#pragma unroll 1
    for (int kt = 1; kt < 9; ++kt) {
        tap_setup(kt, h, w, offb, cg, t);
        tap_load(xb4, t, pf);                              // loads in flight
        mfma_tap(wb + (kt - 1) * COUT * Cc, V[(kt - 1) & 1], wv, ln, acc);
        tap_store(t, pf, (kt & 1) ? vrow1 : vrow0);        // waits loads here
        __syncthreads();
    }
    // epilogue: tap 8 MFMA
    mfma_tap(wb + 8 * COUT * Cc, V[0], wv, ln, acc);

    // epilogue: C/D layout col=lane&15 (pos), row=(lane>>4)*4+reg (o)
    float* outp = out + b * COUT * HW + h * Ww;
#pragma unroll
    for (int mt = 0; mt < 4; ++mt)
#pragma unroll
        for (int nt = 0; nt < 2; ++nt) {
            const int col = w0 + wv * 32 + nt * 16 + (ln & 15);
#pragma unroll
            for (int r = 0; r < 4; ++r) {
                const int o = mt * 16 + (ln >> 4) * 4 + r;
                outp[o * HW + col] = acc[mt][nt][r] + bias[o];
            }
        }
}

extern "C" void kernel_launch(void* const* d_in, const int* in_sizes, int n_in,
                              void* d_out, int out_size, void* d_ws, size_t ws_size,
                              hipStream_t stream) {
    const float* x      = (const float*)d_in[0];
    const float* offset = (const float*)d_in[1];
    const float* weight = (const float*)d_in[2];
    const float* bias   = (const float*)d_in[3];
    float* out = (float*)d_out;

    _Float16* xn = (_Float16*)d_ws;                          // 16.8 MiB NHWC fp16
    unsigned short* wb = (unsigned short*)((char*)d_ws + (size_t)Bb * HW * Cc * 2);

    wtrans<<<dim3((COUT * Cc * 9 + 255) / 256), 256, 0, stream>>>(weight, wb);
    xtrans<<<dim3(Hh, Bb), 256, 0, stream>>>(x, xn);
    dcn_mfma<<<dim3(Ww / 128, Hh, Bb), 256, 0, stream>>>(xn, offset, wb, bias, out);
}

// Round 7
// 203.815 us; speedup vs baseline: 30.0650x; 1.0552x over previous
//
#include <hip/hip_runtime.h>

typedef short short8 __attribute__((ext_vector_type(8)));
typedef float floatx4 __attribute__((ext_vector_type(4)));
typedef _Float16 half2v __attribute__((ext_vector_type(2)));

#define Hh 128
#define Ww 256
#define Cc 64
#define COUT 64
#define Bb 4
#define HW (Hh*Ww)
#define VP 74   // LDS V row stride in shorts: 37 dwords ≡ 5 (mod 32) -> <=2-way (free)

__device__ inline unsigned bf16rne(float f) {
    unsigned u = __float_as_uint(f);
    return (u + 0x7FFF + ((u >> 16) & 1)) >> 16;
}

// weight (o, c, kt) fp32 -> Wb[kt][o][c] bf16 (A-operand friendly: c contiguous)
__global__ void wtrans(const float* __restrict__ src, unsigned short* __restrict__ dst) {
    int i = blockIdx.x * 256 + threadIdx.x;
    if (i >= COUT * Cc * 9) return;
    int kt = i % 9, c = (i / 9) % Cc, o = i / (9 * Cc);
    dst[(kt * COUT + o) * Cc + c] = (unsigned short)bf16rne(src[i]);
}

// x NCHW fp32 -> NHWC fp16. One block per (h,b) row; LDS stride 74 shorts
// (37 dwords, odd) -> conflict-free write phase.
__global__ void xtrans(const float* __restrict__ src, _Float16* __restrict__ dst) {
    __shared__ unsigned short T[256][VP];
    const int h = blockIdx.x, b = blockIdx.y;
    const int tid = threadIdx.x;
    const float* sp = src + (b * Cc * Hh + h) * Ww + tid;   // x[b][.][h][tid]
#pragma unroll
    for (int c2 = 0; c2 < 32; ++c2) {
        const float v0 = sp[(2 * c2) * HW];
        const float v1 = sp[(2 * c2 + 1) * HW];
        half2v hv; hv.x = (_Float16)v0; hv.y = (_Float16)v1;
        *(unsigned*)&T[tid][2 * c2] = *(unsigned*)&hv;
    }
    __syncthreads();
    uint4* drow = (uint4*)(dst + ((size_t)(b * Hh + h) * Ww) * 64);  // 2048 uint4
#pragma unroll
    for (int j = 0; j < 8; ++j) {
        const int idx = j * 256 + tid;        // contiguous 4KB per iteration
        drow[idx] = *(const uint4*)&T[idx >> 3][(idx & 7) * 8];
    }
}

struct Tap {
    float w00, w01, w10, w11;
    int a00, a01, a10, a11;   // corner addresses in uint4 (16B) units
};

__device__ inline void tap_setup(int kt, int h, int w, const float* __restrict__ offb,
                                 int cg, Tap& t) {
    const int ki = kt / 3, kj = kt % 3;
    const float dy = offb[(2 * kt) * HW];
    const float dx = offb[(2 * kt + 1) * HW];
    const float py = (float)(h - 1 + ki) + dy;
    const float px = (float)(w - 1 + kj) + dx;
    const float y0f = floorf(py), x0f = floorf(px);
    const int y0 = (int)y0f, x0 = (int)x0f;
    const float ly = py - y0f, lx = px - x0f;
    const int y1 = y0 + 1, x1 = x0 + 1;
    const bool vy0 = ((unsigned)y0 < Hh), vy1 = ((unsigned)y1 < Hh);
    const bool vx0 = ((unsigned)x0 < Ww), vx1 = ((unsigned)x1 < Ww);
    t.w00 = (vy0 && vx0) ? (1.f - ly) * (1.f - lx) : 0.f;
    t.w01 = (vy0 && vx1) ? (1.f - ly) * lx : 0.f;
    t.w10 = (vy1 && vx0) ? ly * (1.f - lx) : 0.f;
    t.w11 = (vy1 && vx1) ? ly * lx : 0.f;
    const int y0c = min(max(y0, 0), Hh - 1), y1c = min(max(y1, 0), Hh - 1);
    const int x0c = min(max(x0, 0), Ww - 1), x1c = min(max(x1, 0), Ww - 1);
    t.a00 = (y0c * Ww + x0c) * 8 + cg * 2;   // 64ch*2B = 8 uint4/pos; cg chunk = 2
    t.a01 = (y0c * Ww + x1c) * 8 + cg * 2;
    t.a10 = (y1c * Ww + x0c) * 8 + cg * 2;
    t.a11 = (y1c * Ww + x1c) * 8 + cg * 2;
}

// 8 x 16B loads: 4 adjacent lanes (same p, cg=0..3) cover contiguous 128B rows
__device__ inline void tap_load(const uint4* __restrict__ xb4, const Tap& t,
                                unsigned pf[32]) {
#pragma unroll
    for (int j = 0; j < 2; ++j) {
        *(uint4*)&pf[(0 * 2 + j) * 4] = xb4[t.a00 + j];
        *(uint4*)&pf[(1 * 2 + j) * 4] = xb4[t.a01 + j];
        *(uint4*)&pf[(2 * 2 + j) * 4] = xb4[t.a10 + j];
        *(uint4*)&pf[(3 * 2 + j) * 4] = xb4[t.a11 + j];
    }
}

__device__ inline void tap_store(const Tap& t, const unsigned pf[32],
                                 unsigned short* __restrict__ vrow) {
#pragma unroll
    for (int j = 0; j < 2; ++j) {
        unsigned o[4];
#pragma unroll
        for (int s = 0; s < 4; ++s) {
            const half2v h00 = *(const half2v*)&pf[(0 * 2 + j) * 4 + s];
            const half2v h01 = *(const half2v*)&pf[(1 * 2 + j) * 4 + s];
            const half2v h10 = *(const half2v*)&pf[(2 * 2 + j) * 4 + s];
            const half2v h11 = *(const half2v*)&pf[(3 * 2 + j) * 4 + s];
            const float vlo = t.w00 * (float)h00.x + t.w01 * (float)h01.x
                            + t.w10 * (float)h10.x + t.w11 * (float)h11.x;
            const float vhi = t.w00 * (float)h00.y + t.w01 * (float)h01.y
                            + t.w10 * (float)h10.y + t.w11 * (float)h11.y;
            o[s] = bf16rne(vlo) | (bf16rne(vhi) << 16);
        }
        uint4 u; u.x = o[0]; u.y = o[1]; u.z = o[2]; u.w = o[3];
        *(uint4*)(vrow + j * 8) = u;   // ds_write_b128
    }
}

__device__ inline void mfma_tap(const unsigned short* __restrict__ wk,
                                const unsigned short* __restrict__ Vbuf,
                                int wv, int ln, floatx4 acc[4]) {
#pragma unroll
    for (int g = 0; g < 2; ++g) {
        const int pp = wv * 16 + (ln & 15);
        short8 bfrag = *(const short8*)&Vbuf[pp * VP + g * 32 + (ln >> 4) * 8];
#pragma unroll
        for (int mt = 0; mt < 4; ++mt) {
            const int oo = mt * 16 + (ln & 15);
            short8 afrag = *(const short8*)(wk + oo * Cc + g * 32 + (ln >> 4) * 8);
            acc[mt] = __builtin_amdgcn_mfma_f32_16x16x32_bf16(afrag, bfrag, acc[mt], 0, 0, 0);
        }
    }
}

// Implicit GEMM, 64-pos tiles (2048 blocks), software-pipelined taps,
// double-buffered LDS V. 6 blocks/CU: LDS 6x18.9KB=114KB, VGPR cap 85.
__launch_bounds__(256, 6)
__global__ void dcn_mfma(const _Float16* __restrict__ xn,   // NHWC fp16
                         const float* __restrict__ offset,
                         const unsigned short* __restrict__ wb,
                         const float* __restrict__ bias,
                         float* __restrict__ out) {
    __shared__ unsigned short V[2][64 * VP];   // 2 x 9472 B

    const int tid = threadIdx.x;
    const int p   = tid >> 2;     // position (gather role): 4 lanes share one pos
    const int cg  = tid & 3;      // channel chunk 16ch = 32B
    const int wv  = tid >> 6;     // wave id (MFMA role: n-tile wv)
    const int ln  = tid & 63;

    const int b  = blockIdx.z;
    const int h  = blockIdx.y;
    const int w0 = blockIdx.x * 64;
    const int w  = w0 + p;

    const uint4* xb4  = (const uint4*)(xn + (size_t)b * HW * 64);
    const float* offb = offset + b * 18 * HW + h * Ww + w;
    unsigned short* vrow0 = &V[0][p * VP + cg * 16];
    unsigned short* vrow1 = &V[1][p * VP + cg * 16];

    floatx4 acc[4];
#pragma unroll
    for (int mt = 0; mt < 4; ++mt) acc[mt] = (floatx4)0.f;

    unsigned pf[32];
    Tap t;

    // prologue: tap 0
    tap_setup(0, h, w, offb, cg, t);
    tap_load(xb4, t, pf);
    tap_store(t, pf, vrow0);
    __syncthreads();

    // pipeline: issue loads for tap kt, MFMA tap kt-1, pack tap kt, barrier
#pragma unroll 1
    for (int kt = 1; kt < 9; ++kt) {
        tap_setup(kt, h, w, offb, cg, t);
        tap_load(xb4, t, pf);                              // loads in flight
        mfma_tap(wb + (kt - 1) * COUT * Cc, V[(kt - 1) & 1], wv, ln, acc);
        tap_store(t, pf, (kt & 1) ? vrow1 : vrow0);        // waits loads here
        __syncthreads();
    }
    // epilogue: tap 8 MFMA (buffer 0)
    mfma_tap(wb + 8 * COUT * Cc, V[0], wv, ln, acc);

    // epilogue: C/D layout col=lane&15 (pos), row=(lane>>4)*4+reg (o)
    float* outp = out + b * COUT * HW + h * Ww;
    const int col = w0 + wv * 16 + (ln & 15);
#pragma unroll
    for (int mt = 0; mt < 4; ++mt)
#pragma unroll
        for (int r = 0; r < 4; ++r) {
            const int o = mt * 16 + (ln >> 4) * 4 + r;
            outp[o * HW + col] = acc[mt][r] + bias[o];
        }
}

extern "C" void kernel_launch(void* const* d_in, const int* in_sizes, int n_in,
                              void* d_out, int out_size, void* d_ws, size_t ws_size,
                              hipStream_t stream) {
    const float* x      = (const float*)d_in[0];
    const float* offset = (const float*)d_in[1];
    const float* weight = (const float*)d_in[2];
    const float* bias   = (const float*)d_in[3];
    float* out = (float*)d_out;

    _Float16* xn = (_Float16*)d_ws;                          // 16.8 MiB NHWC fp16
    unsigned short* wb = (unsigned short*)((char*)d_ws + (size_t)Bb * HW * Cc * 2);

    wtrans<<<dim3((COUT * Cc * 9 + 255) / 256), 256, 0, stream>>>(weight, wb);
    xtrans<<<dim3(Hh, Bb), 256, 0, stream>>>(x, xn);
    dcn_mfma<<<dim3(Ww / 64, Hh, Bb), 256, 0, stream>>>(xn, offset, wb, bias, out);
}